// Round 13
// baseline (871.886 us; speedup 1.0000x reference)
//
#include <hip/hip_runtime.h>
#include <hip/hip_bf16.h>

// out[n] = b + e_x[n] * sum_m exp(2*GAMMA*dot(x_n,y_m)) * c[m]
// n=16384, m=8192, d=512.
// Round 13: r9/r12 structure at DOUBLE OCCUPANCY. 1024-thread blocks
// (16 waves) x 2 blocks/CU = 8 waves/SIMD (VGPR 56 <= 64 allows it; r12 was
// 4/SIMD). Same per-wave 64x32 tile, B-from-L2-regs, read-only LDS (A 64KB +
// cw 16KB = 80KB), zero main-loop barriers, same XCD/col-half map (B L2
// traffic unchanged). MFMA pipe now oversubscribed 8 waves deep.
//
// Workspace: Xb bf16[16384*512] @0, Ybt bf16[8192*512] @16777216 (frag layout),
//            ex f32[16384] @25165824, cw f32[8192] @25231360.

#define GAMMA 0.002f

typedef __bf16 bf16x8 __attribute__((ext_vector_type(8)));
typedef float  f32x4  __attribute__((ext_vector_type(4)));
typedef __attribute__((address_space(3))) void lds_void_t;
typedef __attribute__((address_space(1))) const void gl_void_t;

// ---------------- prep X: f32 -> bf16 row-major + ex = exp(-g*||x||^2)
__global__ __launch_bounds__(256) void prep_x(const float* __restrict__ src,
                                              __bf16* __restrict__ dst,
                                              float* __restrict__ fac) {
    const int wid  = threadIdx.x >> 6;
    const int lane = threadIdx.x & 63;
    const int row  = blockIdx.x * 4 + wid;
    const float4* s = reinterpret_cast<const float4*>(src + (size_t)row * 512);
    float4 v0 = s[lane * 2];
    float4 v1 = s[lane * 2 + 1];
    float acc = v0.x * v0.x + v0.y * v0.y + v0.z * v0.z + v0.w * v0.w
              + v1.x * v1.x + v1.y * v1.y + v1.z * v1.z + v1.w * v1.w;
    bf16x8 o;
    o[0] = (__bf16)v0.x; o[1] = (__bf16)v0.y; o[2] = (__bf16)v0.z; o[3] = (__bf16)v0.w;
    o[4] = (__bf16)v1.x; o[5] = (__bf16)v1.y; o[6] = (__bf16)v1.z; o[7] = (__bf16)v1.w;
    *reinterpret_cast<bf16x8*>(dst + (size_t)row * 512 + lane * 8) = o;
#pragma unroll
    for (int off = 32; off >= 1; off >>= 1) acc += __shfl_xor(acc, off, 64);
    if (lane == 0) fac[row] = __expf(-GAMMA * acc);
}

// ---------------- prep Y: f32 -> bf16 FRAGMENT layout + cw = exp(-g*||y||^2)*W
// Ybt elem index for (m,k): q=k>>5, cb=m>>4, kslot=(k>>3)&3, col'=m&15:
//   ((q*512 + cb)*512) + (kslot*16 + col')*8 + (k&7)
// -> B-frag (q,cb) read = base + lane*8 elems (contiguous 1KB/wave).
__global__ __launch_bounds__(256) void prep_y(const float* __restrict__ src,
                                              __bf16* __restrict__ dst,
                                              float* __restrict__ fac,
                                              const float* __restrict__ W) {
    const int wid  = threadIdx.x >> 6;
    const int lane = threadIdx.x & 63;
    const int m    = blockIdx.x * 4 + wid;
    const float4* s = reinterpret_cast<const float4*>(src + (size_t)m * 512);
    float4 v0 = s[lane * 2];
    float4 v1 = s[lane * 2 + 1];
    float acc = v0.x * v0.x + v0.y * v0.y + v0.z * v0.z + v0.w * v0.w
              + v1.x * v1.x + v1.y * v1.y + v1.z * v1.z + v1.w * v1.w;
    bf16x8 o;
    o[0] = (__bf16)v0.x; o[1] = (__bf16)v0.y; o[2] = (__bf16)v0.z; o[3] = (__bf16)v0.w;
    o[4] = (__bf16)v1.x; o[5] = (__bf16)v1.y; o[6] = (__bf16)v1.z; o[7] = (__bf16)v1.w;
    const size_t idx = ((size_t)(lane >> 2) * 512 + (m >> 4)) * 512
                     + ((lane & 3) * 16 + (m & 15)) * 8;
    *reinterpret_cast<bf16x8*>(dst + idx) = o;
#pragma unroll
    for (int off = 32; off >= 1; off >>= 1) acc += __shfl_xor(acc, off, 64);
    if (lane == 0) fac[m] = __expf(-GAMMA * acc) * W[m];
}

__global__ void init_out(float* __restrict__ out, const float* __restrict__ b, int n) {
    int i = blockIdx.x * blockDim.x + threadIdx.x;
    if (i < n) out[i] = b[0];
}

// ---------------- LDS (80KB/block): A @0: [q 16][rb 4][1KB] k-major frag
// blocks (lane*16 read, conflict-free); cw @65536: 16KB (block's col-half).

// chunk C 0..127: q = C&15, panel p = C>>4 (8 panels x 512 cols);
// wave owns 2 colblocks (32 cols) per panel.
#define LOADB(B, C) do { \
    const int q_ = (C) & 15, p_ = (C) >> 4; \
    const __bf16* bp_ = Ybt + ((size_t)q_ * 512 + cbgBase + p_ * 32) * 512 + lane8; \
    B[0] = *reinterpret_cast<const bf16x8*>(bp_); \
    B[1] = *reinterpret_cast<const bf16x8*>(bp_ + 512); \
} while (0)

#define READA(A, Q) do { \
    _Pragma("unroll") \
    for (int rb = 0; rb < 4; ++rb) \
        A[rb] = *reinterpret_cast<const bf16x8*>( \
            &smem[(Q) * 4096 + rb * 1024 + lane16]); \
} while (0)

#define MFMA8(A, B) do { \
    __builtin_amdgcn_s_setprio(1); \
    _Pragma("unroll") \
    for (int rb = 0; rb < 4; ++rb) \
        _Pragma("unroll") \
        for (int cb = 0; cb < 2; ++cb) \
            acc[rb][cb] = __builtin_amdgcn_mfma_f32_16x16x32_bf16( \
                A[rb], B[cb], acc[rb][cb], 0, 0, 0); \
    __builtin_amdgcn_s_setprio(0); \
} while (0)

// grid: 512 blocks (2/CU), 1024 threads (16 waves; wave tile 64 rows x 32 cols)
__global__ __launch_bounds__(1024, 8) void rbf_gemm(
    const __bf16* __restrict__ Xb, const __bf16* __restrict__ Ybt,
    const float* __restrict__ ex, const float* __restrict__ cwp,
    float* __restrict__ out) {
    __shared__ __align__(128) char smem[81920];

    const int tid  = threadIdx.x;
    const int wid  = tid >> 6;            // 0..15
    const int lane = tid & 63;

    // XCD map (r9-proven): even XCDs -> col-half 0, odd -> 1; 64 blocks/XCD
    // share one 4MB Ybt half (L2-fit). rg = 64-row group.
    const int pid = blockIdx.x;
    const int xcd = pid & 7;
    const int j   = pid >> 3;                    // 0..63
    const int ch  = xcd & 1;
    const int rg  = (xcd >> 1) * 64 + j;         // 0..255
    const int rowBase = rg * 64;
    const int colBase = ch * 4096;
    const int cbgBase = ch * 256 + wid * 2;      // wave's colblock base per panel

    const int l15 = lane & 15, l4 = lane >> 4;
    const int lane16 = lane * 16;
    const int lane8  = lane * 8;

    // ---- prologue: A panel (64 x 1KB frag blocks; 4 per wave) + cw -> LDS
#pragma unroll
    for (int i = 0; i < 4; ++i) {
        const int blk = wid * 4 + i;
        const int q = blk >> 2, rb = blk & 3;
        const __bf16* src = Xb + (size_t)(rowBase + rb * 16 + l15) * 512 + q * 32 + l4 * 8;
        __builtin_amdgcn_global_load_lds((gl_void_t*)src,
            (lds_void_t*)(smem + q * 4096 + rb * 1024), 16, 0, 0);
    }
    __builtin_amdgcn_global_load_lds(
        (gl_void_t*)(cwp + colBase + wid * 256 + lane * 4),
        (lds_void_t*)(smem + 65536 + wid * 1024), 16, 0, 0);
    asm volatile("s_waitcnt vmcnt(0)");
    __builtin_amdgcn_s_barrier();        // the only barrier; LDS read-only after

    f32x4 acc[4][2] = {};
    float rowsum[4][4] = {};

    bf16x8 A0[4], A1[4], B0[2], B1[2];
    LOADB(B0, 0);

    // ---- main: 128 chunks (8 panels x 16 kchunks), no barriers, reg dbuf.
    for (int cc = 0; cc < 64; ++cc) {
        const int ce = 2 * cc, co = 2 * cc + 1;
        LOADB(B1, co);
        READA(A0, ce & 15);
        MFMA8(A0, B0);
        LOADB(B0, (co + 1) & 127);
        READA(A1, co & 15);
        MFMA8(A1, B1);
        if ((cc & 7) == 7) {
            // ---- per-panel epilogue: acc holds full K=512; pure VALU + LDS cw
            const int p = cc >> 3;
            float cv[2];
#pragma unroll
            for (int cb = 0; cb < 2; ++cb)
                cv[cb] = *reinterpret_cast<const float*>(
                    &smem[65536 + (p * 512 + wid * 32 + cb * 16 + l15) * 4]);
#pragma unroll
            for (int rb = 0; rb < 4; ++rb)
#pragma unroll
                for (int i2 = 0; i2 < 4; ++i2) {
                    rowsum[rb][i2] += __expf(0.004f * acc[rb][0][i2]) * cv[0]
                                    + __expf(0.004f * acc[rb][1][i2]) * cv[1];
                }
#pragma unroll
            for (int rb = 0; rb < 4; ++rb) {
                acc[rb][0] = (f32x4){0.f, 0.f, 0.f, 0.f};
                acc[rb][1] = (f32x4){0.f, 0.f, 0.f, 0.f};
            }
        }
    }

    // ---- final: 16-lane reduce + one atomic per (wave, n); out pre-init'd to b
#pragma unroll
    for (int rb = 0; rb < 4; ++rb)
#pragma unroll
        for (int i2 = 0; i2 < 4; ++i2) {
            float s = rowsum[rb][i2];
#pragma unroll
            for (int off = 1; off < 16; off <<= 1) s += __shfl_xor(s, off, 64);
            if (l15 == 0) {
                const int n = rowBase + rb * 16 + l4 * 4 + i2;
                atomicAdd(&out[n], ex[n] * s);
            }
        }
}

extern "C" void kernel_launch(void* const* d_in, const int* in_sizes, int n_in,
                              void* d_out, int out_size, void* d_ws, size_t ws_size,
                              hipStream_t stream) {
    const float* X = (const float*)d_in[0];   // 16384 x 512
    const float* Y = (const float*)d_in[1];   //  8192 x 512
    const float* W = (const float*)d_in[2];   // 8192
    const float* b = (const float*)d_in[3];   // 1
    float* out = (float*)d_out;               // 16384

    char* ws = (char*)d_ws;
    __bf16* Xb  = (__bf16*)(ws);
    __bf16* Ybt = (__bf16*)(ws + 16777216);
    float*  ex  = (float*)(ws + 16777216 + 8388608);
    float*  cw  = (float*)(ws + 16777216 + 8388608 + 65536);

    prep_x<<<4096, 256, 0, stream>>>(X, Xb, ex);
    prep_y<<<2048, 256, 0, stream>>>(Y, Ybt, cw, W);
    init_out<<<64, 256, 0, stream>>>(out, b, 16384);
    rbf_gemm<<<512, 1024, 0, stream>>>(Xb, Ybt, ex, cw, out);
}

// Round 14
// 150.224 us; speedup vs baseline: 5.8039x; 5.8039x over previous
//
#include <hip/hip_runtime.h>
#include <hip/hip_bf16.h>

// out[n] = b + e_x[n] * sum_m exp(2*GAMMA*dot(x_n,y_m)) * c[m]
// n=16384, m=8192, d=512.
// Round 14: r9/r12 structure (64x32 wave tile, B-from-L2-regs, read-only LDS,
// no main-loop barriers, 512 thr x 2 blocks/CU) + INLINE-ASM PIPELINED B:
// global_load_dwordx4 issued 3 chunk-slots ahead into 4 named buffers,
// s_waitcnt vmcnt(6) + sched_barrier(0) before each MFMA (counted-vmcnt, the
// HK/AITER pattern the compiler can't collapse). r13 lesson: never starve
// VGPR below the ~110-reg working set.
//
// Workspace: Xb bf16[16384*512] @0, Ybt bf16[8192*512] @16777216 (frag layout),
//            ex f32[16384] @25165824, cw f32[8192] @25231360.

#define GAMMA 0.002f

typedef __bf16 bf16x8 __attribute__((ext_vector_type(8)));
typedef float  f32x4  __attribute__((ext_vector_type(4)));
typedef __attribute__((address_space(3))) void lds_void_t;
typedef __attribute__((address_space(1))) const void gl_void_t;

// ---------------- prep X: f32 -> bf16 row-major + ex = exp(-g*||x||^2)
__global__ __launch_bounds__(256) void prep_x(const float* __restrict__ src,
                                              __bf16* __restrict__ dst,
                                              float* __restrict__ fac) {
    const int wid  = threadIdx.x >> 6;
    const int lane = threadIdx.x & 63;
    const int row  = blockIdx.x * 4 + wid;
    const float4* s = reinterpret_cast<const float4*>(src + (size_t)row * 512);
    float4 v0 = s[lane * 2];
    float4 v1 = s[lane * 2 + 1];
    float acc = v0.x * v0.x + v0.y * v0.y + v0.z * v0.z + v0.w * v0.w
              + v1.x * v1.x + v1.y * v1.y + v1.z * v1.z + v1.w * v1.w;
    bf16x8 o;
    o[0] = (__bf16)v0.x; o[1] = (__bf16)v0.y; o[2] = (__bf16)v0.z; o[3] = (__bf16)v0.w;
    o[4] = (__bf16)v1.x; o[5] = (__bf16)v1.y; o[6] = (__bf16)v1.z; o[7] = (__bf16)v1.w;
    *reinterpret_cast<bf16x8*>(dst + (size_t)row * 512 + lane * 8) = o;
#pragma unroll
    for (int off = 32; off >= 1; off >>= 1) acc += __shfl_xor(acc, off, 64);
    if (lane == 0) fac[row] = __expf(-GAMMA * acc);
}

// ---------------- prep Y: f32 -> bf16 FRAGMENT layout + cw = exp(-g*||y||^2)*W
__global__ __launch_bounds__(256) void prep_y(const float* __restrict__ src,
                                              __bf16* __restrict__ dst,
                                              float* __restrict__ fac,
                                              const float* __restrict__ W) {
    const int wid  = threadIdx.x >> 6;
    const int lane = threadIdx.x & 63;
    const int m    = blockIdx.x * 4 + wid;
    const float4* s = reinterpret_cast<const float4*>(src + (size_t)m * 512);
    float4 v0 = s[lane * 2];
    float4 v1 = s[lane * 2 + 1];
    float acc = v0.x * v0.x + v0.y * v0.y + v0.z * v0.z + v0.w * v0.w
              + v1.x * v1.x + v1.y * v1.y + v1.z * v1.z + v1.w * v1.w;
    bf16x8 o;
    o[0] = (__bf16)v0.x; o[1] = (__bf16)v0.y; o[2] = (__bf16)v0.z; o[3] = (__bf16)v0.w;
    o[4] = (__bf16)v1.x; o[5] = (__bf16)v1.y; o[6] = (__bf16)v1.z; o[7] = (__bf16)v1.w;
    const size_t idx = ((size_t)(lane >> 2) * 512 + (m >> 4)) * 512
                     + ((lane & 3) * 16 + (m & 15)) * 8;
    *reinterpret_cast<bf16x8*>(dst + idx) = o;
#pragma unroll
    for (int off = 32; off >= 1; off >>= 1) acc += __shfl_xor(acc, off, 64);
    if (lane == 0) fac[m] = __expf(-GAMMA * acc) * W[m];
}

__global__ void init_out(float* __restrict__ out, const float* __restrict__ b, int n) {
    int i = blockIdx.x * blockDim.x + threadIdx.x;
    if (i < n) out[i] = b[0];
}

// ---------------- LDS (80KB/block): A @0: [q 16][rb 4][1KB] k-major frag
// blocks (lane*16 read, conflict-free); cw @65536: 16KB (block's col-half).

// chunk C 0..255: q = C&15, panel p = C>>4; wave owns 2 colblocks (32 cols).
// Inline-asm pinned issue: one asm = both dwordx4 of the chunk.
#define LOADB_ASM(B, C) do { \
    const __bf16* bp_ = Ybt + ((size_t)((C) & 15) * 512 + cbgBase + ((C) >> 4) * 16) * 512 + lane8; \
    asm volatile("global_load_dwordx4 %0, %2, off\n\t" \
                 "global_load_dwordx4 %1, %2, off offset:1024" \
                 : "=v"(B[0]), "=v"(B[1]) : "v"(bp_)); \
} while (0)

#define READA(A, Q) do { \
    _Pragma("unroll") \
    for (int rb = 0; rb < 4; ++rb) \
        A[rb] = *reinterpret_cast<const bf16x8*>( \
            &smem[(Q) * 4096 + rb * 1024 + lane16]); \
} while (0)

#define MFMA8(A, B) do { \
    __builtin_amdgcn_s_setprio(1); \
    _Pragma("unroll") \
    for (int rb = 0; rb < 4; ++rb) \
        _Pragma("unroll") \
        for (int cb = 0; cb < 2; ++cb) \
            acc[rb][cb] = __builtin_amdgcn_mfma_f32_16x16x32_bf16( \
                A[rb], B[cb], acc[rb][cb], 0, 0, 0); \
    __builtin_amdgcn_s_setprio(0); \
} while (0)

// One slot: issue loads for chunk c+3, read A(c), wait chunk c's loads
// (vmcnt(6): 3 chunks = 6 loads stay in flight), fence, MFMA(c).
#define SLOT(BCUR, BNXT, CLOAD, Q) do { \
    LOADB_ASM(BNXT, CLOAD); \
    READA(A, Q); \
    asm volatile("s_waitcnt vmcnt(6)"); \
    __builtin_amdgcn_sched_barrier(0); \
    MFMA8(A, BCUR); \
} while (0)

// grid: 512 blocks (2/CU), 512 threads (8 waves = 8 col-eighths; tile 64x32/wave)
__global__ __launch_bounds__(512, 4) void rbf_gemm(
    const __bf16* __restrict__ Xb, const __bf16* __restrict__ Ybt,
    const float* __restrict__ ex, const float* __restrict__ cwp,
    float* __restrict__ out) {
    __shared__ __align__(128) char smem[81920];

    const int tid  = threadIdx.x;
    const int wid  = tid >> 6;
    const int lane = tid & 63;

    // XCD map (r9-proven): even XCDs -> col-half 0, odd -> 1; 64 blocks/XCD
    // share one 4MB Ybt half (L2-fit). rg = 64-row group.
    const int pid = blockIdx.x;
    const int xcd = pid & 7;
    const int j   = pid >> 3;                    // 0..63
    const int ch  = xcd & 1;
    const int rg  = (xcd >> 1) * 64 + j;         // 0..255
    const int rowBase = rg * 64;
    const int colBase = ch * 4096;
    const int cbgBase = ch * 256 + wid * 2;      // wave's colblock base per panel

    const int l15 = lane & 15, l4 = lane >> 4;
    const int lane16 = lane * 16;
    const int lane8  = lane * 8;

    // ---- prologue: A panel (64 x 1KB frag blocks, gather src) + cw -> LDS
#pragma unroll
    for (int i = 0; i < 8; ++i) {
        const int blk = wid * 8 + i;
        const int q = blk >> 2, rb = blk & 3;
        const __bf16* src = Xb + (size_t)(rowBase + rb * 16 + l15) * 512 + q * 32 + l4 * 8;
        __builtin_amdgcn_global_load_lds((gl_void_t*)src,
            (lds_void_t*)(smem + q * 4096 + rb * 1024), 16, 0, 0);
    }
#pragma unroll
    for (int i = 0; i < 2; ++i)
        __builtin_amdgcn_global_load_lds(
            (gl_void_t*)(cwp + colBase + wid * 512 + i * 256 + lane * 4),
            (lds_void_t*)(smem + 65536 + wid * 2048 + i * 1024), 16, 0, 0);
    asm volatile("s_waitcnt vmcnt(0)");
    __builtin_amdgcn_s_barrier();        // the only barrier; LDS read-only after

    f32x4 acc[4][2] = {};
    float rowsum[4][4] = {};

    bf16x8 A[4], B0[2], B1[2], B2[2], B3[2];
    LOADB_ASM(B0, 0);
    LOADB_ASM(B1, 1);
    LOADB_ASM(B2, 2);                    // 6 loads in flight entering the loop

    // ---- main: 256 chunks (16 panels x 16 kchunks), asm-pinned 4-deep B
    // pipeline, no barriers.
    for (int cc = 0; cc < 64; ++cc) {
        const int c0 = 4 * cc;
        SLOT(B0, B3, (c0 + 3) & 255, c0 & 15);
        SLOT(B1, B0, (c0 + 4) & 255, (c0 + 1) & 15);
        SLOT(B2, B1, (c0 + 5) & 255, (c0 + 2) & 15);
        SLOT(B3, B2, (c0 + 6) & 255, (c0 + 3) & 15);
        if ((cc & 3) == 3) {
            // ---- per-panel epilogue: acc holds full K=512; pure VALU + LDS cw
            const int p = cc >> 2;
            float cv[2];
#pragma unroll
            for (int cb = 0; cb < 2; ++cb)
                cv[cb] = *reinterpret_cast<const float*>(
                    &smem[65536 + (p * 256 + wid * 32 + cb * 16 + l15) * 4]);
#pragma unroll
            for (int rb = 0; rb < 4; ++rb)
#pragma unroll
                for (int i2 = 0; i2 < 4; ++i2) {
                    rowsum[rb][i2] += __expf(0.004f * acc[rb][0][i2]) * cv[0]
                                    + __expf(0.004f * acc[rb][1][i2]) * cv[1];
                }
#pragma unroll
            for (int rb = 0; rb < 4; ++rb) {
                acc[rb][0] = (f32x4){0.f, 0.f, 0.f, 0.f};
                acc[rb][1] = (f32x4){0.f, 0.f, 0.f, 0.f};
            }
        }
    }

    // ---- final: 16-lane reduce + one atomic per (wave, n); out pre-init'd to b
#pragma unroll
    for (int rb = 0; rb < 4; ++rb)
#pragma unroll
        for (int i2 = 0; i2 < 4; ++i2) {
            float s = rowsum[rb][i2];
#pragma unroll
            for (int off = 1; off < 16; off <<= 1) s += __shfl_xor(s, off, 64);
            if (l15 == 0) {
                const int n = rowBase + rb * 16 + l4 * 4 + i2;
                atomicAdd(&out[n], ex[n] * s);
            }
        }
}

extern "C" void kernel_launch(void* const* d_in, const int* in_sizes, int n_in,
                              void* d_out, int out_size, void* d_ws, size_t ws_size,
                              hipStream_t stream) {
    const float* X = (const float*)d_in[0];   // 16384 x 512
    const float* Y = (const float*)d_in[1];   //  8192 x 512
    const float* W = (const float*)d_in[2];   // 8192
    const float* b = (const float*)d_in[3];   // 1
    float* out = (float*)d_out;               // 16384

    char* ws = (char*)d_ws;
    __bf16* Xb  = (__bf16*)(ws);
    __bf16* Ybt = (__bf16*)(ws + 16777216);
    float*  ex  = (float*)(ws + 16777216 + 8388608);
    float*  cw  = (float*)(ws + 16777216 + 8388608 + 65536);

    prep_x<<<4096, 256, 0, stream>>>(X, Xb, ex);
    prep_y<<<2048, 256, 0, stream>>>(Y, Ybt, cw, W);
    init_out<<<64, 256, 0, stream>>>(out, b, 16384);
    rbf_gemm<<<512, 512, 0, stream>>>(Xb, Ybt, ex, cw, out);
}

// Round 15
// 149.040 us; speedup vs baseline: 5.8500x; 1.0079x over previous
//
#include <hip/hip_runtime.h>
#include <hip/hip_bf16.h>

// out[n] = b + e_x[n] * sum_m exp(2*GAMMA*dot(x_n,y_m)) * c[m]
// n=16384, m=8192, d=512.
// Round 15: r14 + ASM A DOUBLE-BUFFER. r14 (asm B pipeline) was null ->
// B latency was not the bind; the serial A-path (compiler schedules plain
// ds_reads at their MFMAs -> ~156cyc exposed latency per chunk) is. Now both
// operands pinned: ds_read_b128(c+1) issued at slot-c top into alternate A
// set; one combined s_waitcnt vmcnt(6) lgkmcnt(4) + sched_barrier(0) per
// slot. 2 A-sets x 4 B-sets, 4-slot unroll.
//
// Workspace: Xb bf16[16384*512] @0, Ybt bf16[8192*512] @16777216 (frag layout),
//            ex f32[16384] @25165824, cw f32[8192] @25231360.

#define GAMMA 0.002f

typedef __bf16 bf16x8 __attribute__((ext_vector_type(8)));
typedef float  f32x4  __attribute__((ext_vector_type(4)));
typedef __attribute__((address_space(3))) void lds_void_t;
typedef __attribute__((address_space(1))) const void gl_void_t;

// ---------------- prep X: f32 -> bf16 row-major + ex = exp(-g*||x||^2)
__global__ __launch_bounds__(256) void prep_x(const float* __restrict__ src,
                                              __bf16* __restrict__ dst,
                                              float* __restrict__ fac) {
    const int wid  = threadIdx.x >> 6;
    const int lane = threadIdx.x & 63;
    const int row  = blockIdx.x * 4 + wid;
    const float4* s = reinterpret_cast<const float4*>(src + (size_t)row * 512);
    float4 v0 = s[lane * 2];
    float4 v1 = s[lane * 2 + 1];
    float acc = v0.x * v0.x + v0.y * v0.y + v0.z * v0.z + v0.w * v0.w
              + v1.x * v1.x + v1.y * v1.y + v1.z * v1.z + v1.w * v1.w;
    bf16x8 o;
    o[0] = (__bf16)v0.x; o[1] = (__bf16)v0.y; o[2] = (__bf16)v0.z; o[3] = (__bf16)v0.w;
    o[4] = (__bf16)v1.x; o[5] = (__bf16)v1.y; o[6] = (__bf16)v1.z; o[7] = (__bf16)v1.w;
    *reinterpret_cast<bf16x8*>(dst + (size_t)row * 512 + lane * 8) = o;
#pragma unroll
    for (int off = 32; off >= 1; off >>= 1) acc += __shfl_xor(acc, off, 64);
    if (lane == 0) fac[row] = __expf(-GAMMA * acc);
}

// ---------------- prep Y: f32 -> bf16 FRAGMENT layout + cw = exp(-g*||y||^2)*W
__global__ __launch_bounds__(256) void prep_y(const float* __restrict__ src,
                                              __bf16* __restrict__ dst,
                                              float* __restrict__ fac,
                                              const float* __restrict__ W) {
    const int wid  = threadIdx.x >> 6;
    const int lane = threadIdx.x & 63;
    const int m    = blockIdx.x * 4 + wid;
    const float4* s = reinterpret_cast<const float4*>(src + (size_t)m * 512);
    float4 v0 = s[lane * 2];
    float4 v1 = s[lane * 2 + 1];
    float acc = v0.x * v0.x + v0.y * v0.y + v0.z * v0.z + v0.w * v0.w
              + v1.x * v1.x + v1.y * v1.y + v1.z * v1.z + v1.w * v1.w;
    bf16x8 o;
    o[0] = (__bf16)v0.x; o[1] = (__bf16)v0.y; o[2] = (__bf16)v0.z; o[3] = (__bf16)v0.w;
    o[4] = (__bf16)v1.x; o[5] = (__bf16)v1.y; o[6] = (__bf16)v1.z; o[7] = (__bf16)v1.w;
    const size_t idx = ((size_t)(lane >> 2) * 512 + (m >> 4)) * 512
                     + ((lane & 3) * 16 + (m & 15)) * 8;
    *reinterpret_cast<bf16x8*>(dst + idx) = o;
#pragma unroll
    for (int off = 32; off >= 1; off >>= 1) acc += __shfl_xor(acc, off, 64);
    if (lane == 0) fac[m] = __expf(-GAMMA * acc) * W[m];
}

__global__ void init_out(float* __restrict__ out, const float* __restrict__ b, int n) {
    int i = blockIdx.x * blockDim.x + threadIdx.x;
    if (i < n) out[i] = b[0];
}

// ---------------- LDS (80KB/block): A @0: [q 16][rb 4][1KB] k-major frag
// blocks (lane*16 read, conflict-free); cw @65536: 16KB (block's col-half).

// chunk C 0..255: q = C&15, panel p = C>>4; wave owns 2 colblocks (32 cols).
#define LOADB_ASM(B, C) do { \
    const __bf16* bp_ = Ybt + ((size_t)((C) & 15) * 512 + cbgBase + ((C) >> 4) * 16) * 512 + lane8; \
    asm volatile("global_load_dwordx4 %0, %2, off\n\t" \
                 "global_load_dwordx4 %1, %2, off offset:1024" \
                 : "=v"(B[0]), "=v"(B[1]) : "v"(bp_)); \
} while (0)

// asm A read: 4 x ds_read_b128 of kchunk QN (addr vgpr + imm offsets).
#define READA_ASM(A, QN) do { \
    const unsigned aaddr_ = ldsA + (unsigned)(QN) * 4096u; \
    asm volatile("ds_read_b128 %0, %4 offset:0\n\t" \
                 "ds_read_b128 %1, %4 offset:1024\n\t" \
                 "ds_read_b128 %2, %4 offset:2048\n\t" \
                 "ds_read_b128 %3, %4 offset:3072" \
                 : "=&v"(A[0]), "=&v"(A[1]), "=&v"(A[2]), "=&v"(A[3]) \
                 : "v"(aaddr_)); \
} while (0)

#define MFMA8(A, B) do { \
    __builtin_amdgcn_s_setprio(1); \
    _Pragma("unroll") \
    for (int rb = 0; rb < 4; ++rb) \
        _Pragma("unroll") \
        for (int cb = 0; cb < 2; ++cb) \
            acc[rb][cb] = __builtin_amdgcn_mfma_f32_16x16x32_bf16( \
                A[rb], B[cb], acc[rb][cb], 0, 0, 0); \
    __builtin_amdgcn_s_setprio(0); \
} while (0)

// One slot (chunk c): issue A(c+1) + B(c+3); wait exactly A(c) (lgkm<=4) and
// B(c) (vm<=6); fence; MFMA(c).
#define SLOT(BCUR, BNXT, CLOAD, ACUR, ANXT, QNXT) do { \
    READA_ASM(ANXT, QNXT); \
    LOADB_ASM(BNXT, CLOAD); \
    asm volatile("s_waitcnt vmcnt(6) lgkmcnt(4)"); \
    __builtin_amdgcn_sched_barrier(0); \
    MFMA8(ACUR, BCUR); \
} while (0)

// grid: 512 blocks (2/CU), 512 threads (8 waves = 8 col-eighths; tile 64x32/wave)
__global__ __launch_bounds__(512, 4) void rbf_gemm(
    const __bf16* __restrict__ Xb, const __bf16* __restrict__ Ybt,
    const float* __restrict__ ex, const float* __restrict__ cwp,
    float* __restrict__ out) {
    __shared__ __align__(128) char smem[81920];

    const int tid  = threadIdx.x;
    const int wid  = tid >> 6;
    const int lane = tid & 63;

    // XCD map (r9-proven): even XCDs -> col-half 0, odd -> 1; 64 blocks/XCD
    // share one 4MB Ybt half (L2-fit). rg = 64-row group.
    const int pid = blockIdx.x;
    const int xcd = pid & 7;
    const int j   = pid >> 3;                    // 0..63
    const int ch  = xcd & 1;
    const int rg  = (xcd >> 1) * 64 + j;         // 0..255
    const int rowBase = rg * 64;
    const int colBase = ch * 4096;
    const int cbgBase = ch * 256 + wid * 2;      // wave's colblock base per panel

    const int l15 = lane & 15, l4 = lane >> 4;
    const int lane16 = lane * 16;
    const int lane8  = lane * 8;
    const unsigned ldsA = (unsigned)(uintptr_t)(lds_void_t*)(smem + lane16);

    // ---- prologue: A panel (64 x 1KB frag blocks, gather src) + cw -> LDS
#pragma unroll
    for (int i = 0; i < 8; ++i) {
        const int blk = wid * 8 + i;
        const int q = blk >> 2, rb = blk & 3;
        const __bf16* src = Xb + (size_t)(rowBase + rb * 16 + l15) * 512 + q * 32 + l4 * 8;
        __builtin_amdgcn_global_load_lds((gl_void_t*)src,
            (lds_void_t*)(smem + q * 4096 + rb * 1024), 16, 0, 0);
    }
#pragma unroll
    for (int i = 0; i < 2; ++i)
        __builtin_amdgcn_global_load_lds(
            (gl_void_t*)(cwp + colBase + wid * 512 + i * 256 + lane * 4),
            (lds_void_t*)(smem + 65536 + wid * 2048 + i * 1024), 16, 0, 0);
    asm volatile("s_waitcnt vmcnt(0)");
    __builtin_amdgcn_s_barrier();        // the only barrier; LDS read-only after

    f32x4 acc[4][2] = {};
    float rowsum[4][4] = {};

    bf16x8 A0[4], A1[4], B0[2], B1[2], B2[2], B3[2];
    READA_ASM(A0, 0);                    // lgkm: 4 outstanding
    LOADB_ASM(B0, 0);
    LOADB_ASM(B1, 1);
    LOADB_ASM(B2, 2);                    // vm: 6 outstanding

    // ---- main: 256 chunks (16 panels x 16 kchunks), fully asm-pinned
    // A(2-deep) + B(4-deep) pipelines, no barriers.
    for (int cc = 0; cc < 64; ++cc) {
        const int c0 = 4 * cc;
        SLOT(B0, B3, (c0 + 3) & 255, A0, A1, (c0 + 1) & 15);
        SLOT(B1, B0, (c0 + 4) & 255, A1, A0, (c0 + 2) & 15);
        SLOT(B2, B1, (c0 + 5) & 255, A0, A1, (c0 + 3) & 15);
        SLOT(B3, B2, (c0 + 6) & 255, A1, A0, (c0 + 4) & 15);
        if ((cc & 3) == 3) {
            // ---- per-panel epilogue: acc holds full K=512; pure VALU + LDS cw
            const int p = cc >> 2;
            float cv[2];
#pragma unroll
            for (int cb = 0; cb < 2; ++cb)
                cv[cb] = *reinterpret_cast<const float*>(
                    &smem[65536 + (p * 256 + wid * 32 + cb * 16 + l15) * 4]);
#pragma unroll
            for (int rb = 0; rb < 4; ++rb)
#pragma unroll
                for (int i2 = 0; i2 < 4; ++i2) {
                    rowsum[rb][i2] += __expf(0.004f * acc[rb][0][i2]) * cv[0]
                                    + __expf(0.004f * acc[rb][1][i2]) * cv[1];
                }
#pragma unroll
            for (int rb = 0; rb < 4; ++rb) {
                acc[rb][0] = (f32x4){0.f, 0.f, 0.f, 0.f};
                acc[rb][1] = (f32x4){0.f, 0.f, 0.f, 0.f};
            }
        }
    }
    asm volatile("s_waitcnt vmcnt(0) lgkmcnt(0)");  // drain untracked asm loads

    // ---- final: 16-lane reduce + one atomic per (wave, n); out pre-init'd to b
#pragma unroll
    for (int rb = 0; rb < 4; ++rb)
#pragma unroll
        for (int i2 = 0; i2 < 4; ++i2) {
            float s = rowsum[rb][i2];
#pragma unroll
            for (int off = 1; off < 16; off <<= 1) s += __shfl_xor(s, off, 64);
            if (l15 == 0) {
                const int n = rowBase + rb * 16 + l4 * 4 + i2;
                atomicAdd(&out[n], ex[n] * s);
            }
        }
}

extern "C" void kernel_launch(void* const* d_in, const int* in_sizes, int n_in,
                              void* d_out, int out_size, void* d_ws, size_t ws_size,
                              hipStream_t stream) {
    const float* X = (const float*)d_in[0];   // 16384 x 512
    const float* Y = (const float*)d_in[1];   //  8192 x 512
    const float* W = (const float*)d_in[2];   // 8192
    const float* b = (const float*)d_in[3];   // 1
    float* out = (float*)d_out;               // 16384

    char* ws = (char*)d_ws;
    __bf16* Xb  = (__bf16*)(ws);
    __bf16* Ybt = (__bf16*)(ws + 16777216);
    float*  ex  = (float*)(ws + 16777216 + 8388608);
    float*  cw  = (float*)(ws + 16777216 + 8388608 + 65536);

    prep_x<<<4096, 256, 0, stream>>>(X, Xb, ex);
    prep_y<<<2048, 256, 0, stream>>>(Y, Ybt, cw, W);
    init_out<<<64, 256, 0, stream>>>(out, b, 16384);
    rbf_gemm<<<512, 512, 0, stream>>>(Xb, Ybt, ex, cw, out);
}